// Round 8
// baseline (161.222 us; speedup 1.0000x reference)
//
#include <hip/hip_runtime.h>

// Sinkhorn top-k, sorted-value domain, x <- 1/(Mx), 200 apps.
// R8: barrier-free wave-per-batch iteration (R7), but K streams from LDS in
// chunk-major layout Klds[chunk][lane] (lane-stride-16B ds_read_b128,
// conflict-free) instead of living in an AGPR-parked register array --
// R7's counters showed ~1 v_accvgpr_read per fdot2 (VOP3P can't source
// AGPRs), doubling VALU issue. x stays in 4 VGPRs/lane; window via
// wave_shr1/wave_shl1 DPP (validated R7). No s_barrier in the loop.

#define N      512
#define BATCH  16
#define KTOP   50
#define NAPPS  200         // 100 iterations x (col + row) - exact iterate count
#define COEF   1442.6950408889634f   // log2(e) / EPSILON, EPSILON = 1e-3
#define NCHUNK 40          // 8 rows x 5 chunks of 4 dwords (8 halves) each

typedef _Float16 h2 __attribute__((ext_vector_type(2)));

static __device__ __forceinline__ h2 pack2(float a, float b) {
    return __builtin_bit_cast(h2, __builtin_amdgcn_cvt_pkrtz(a, b));
}
// lane i <- lane i-1 (zero into lane 0)
static __device__ __forceinline__ unsigned shr1(unsigned v) {
    return (unsigned)__builtin_amdgcn_update_dpp(0, (int)v, 0x138, 0xF, 0xF, true);
}
// lane i <- lane i+1 (zero into lane 63)
static __device__ __forceinline__ unsigned shl1(unsigned v) {
    return (unsigned)__builtin_amdgcn_update_dpp(0, (int)v, 0x130, 0xF, 0xF, true);
}

__global__ __launch_bounds__(64, 1)
void sinkhorn_topk_kernel(const float* __restrict__ scores,
                          float* __restrict__ out) {
    __shared__ __align__(16) float tv[N];        // sorted values, descending
    __shared__ int                 ti[N];        // original index of each rank
    __shared__ __align__(16) uint4 Klds[NCHUNK * 64];  // chunk-major K band

    const int lane = threadIdx.x;           // 0..63
    const int b    = blockIdx.x;

    ((float4*)tv)[2 * lane]     = ((const float4*)(scores + b * N))[2 * lane];
    ((float4*)tv)[2 * lane + 1] = ((const float4*)(scores + b * N))[2 * lane + 1];
#pragma unroll
    for (int r = 0; r < 8; ++r) ti[8 * lane + r] = 8 * lane + r;
    __syncthreads();

    // ---- bitonic sort, descending; 64 lanes x 4 compare-exchanges/step ----
    for (int k = 2; k <= N; k <<= 1) {
        for (int j = k >> 1; j > 0; j >>= 1) {
#pragma unroll
            for (int e = 0; e < 4; ++e) {
                int q = lane + e * 64;                 // pair id 0..255
                int i = ((q & ~(j - 1)) << 1) | (q & (j - 1));
                int p = i | j;
                float va = tv[i], vb = tv[p];
                bool up = ((i & k) == 0);
                bool sw = up ? (va < vb) : (va > vb);
                if (sw) {
                    tv[i] = vb; tv[p] = va;
                    int t_ = ti[i]; ti[i] = ti[p]; ti[p] = t_;
                }
            }
            __syncthreads();
        }
    }

    // ---- K band: rows 8l..8l+7, cols 8l-16..8l+23; write chunk-major ----
    const int r0    = 8 * lane;
    const int gbase = r0 - 16;
    float trow[8];
#pragma unroll
    for (int r = 0; r < 8; ++r) trow[r] = tv[r0 + r];

#pragma unroll
    for (int r = 0; r < 8; ++r) {
#pragma unroll
        for (int mb = 0; mb < 5; ++mb) {
            unsigned cd[4];
#pragma unroll
            for (int j = 0; j < 4; ++j) {
                int m  = 4 * mb + j;
                int g0 = gbase + 2 * m, g1 = g0 + 1;
                int c0 = min(max(g0, 0), N - 1), c1 = min(max(g1, 0), N - 1);
                float s0 = tv[c0], s1 = tv[c1];
                float d0 = trow[r] - s0, d1 = trow[r] - s1;
                cd[j] = __builtin_bit_cast(unsigned,
                          pack2(exp2f(-COEF * d0 * d0), exp2f(-COEF * d1 * d1)));
            }
            Klds[(r * 5 + mb) * 64 + lane] = make_uint4(cd[0], cd[1], cd[2], cd[3]);
        }
    }
    // no barrier needed: each lane reads back only its own chunks

    // ---- iterate in registers: x fp16, 8 rows/lane = 4 dwords ----
    unsigned x[4] = {0x3C003C00u, 0x3C003C00u, 0x3C003C00u, 0x3C003C00u};
    unsigned w[20];                          // 40-half window, dwords
    const uint4* Kl = Klds + lane;

    for (int t = 0; t < NAPPS; ++t) {
#pragma unroll
        for (int k = 0; k < 4; ++k) {
            w[8 + k]  = x[k];                // own block (cols 8l..8l+7)
            w[4 + k]  = shr1(x[k]);          // lane l-1
            w[12 + k] = shl1(x[k]);          // lane l+1
        }
#pragma unroll
        for (int k = 0; k < 4; ++k) {
            w[k]      = shr1(w[4 + k]);      // lane l-2
            w[16 + k] = shl1(w[12 + k]);     // lane l+2
        }
        float acc[8] = {0.f, 0.f, 0.f, 0.f, 0.f, 0.f, 0.f, 0.f};
#pragma unroll
        for (int mb = 0; mb < 5; ++mb) {
            uint4 kc[8];
#pragma unroll
            for (int r = 0; r < 8; ++r)
                kc[r] = Kl[(r * 5 + mb) * 64];       // ds_read_b128, imm offset
#pragma unroll
            for (int j = 0; j < 4; ++j) {
                h2 wm = __builtin_bit_cast(h2, w[4 * mb + j]);
#pragma unroll
                for (int r = 0; r < 8; ++r) {
                    unsigned kd = (j == 0) ? kc[r].x : (j == 1) ? kc[r].y
                                : (j == 2) ? kc[r].z : kc[r].w;
                    acc[r] = __builtin_amdgcn_fdot2(
                               __builtin_bit_cast(h2, kd), wm, acc[r], false);
                }
            }
        }
#pragma unroll
        for (int k = 0; k < 4; ++k)
            x[k] = __builtin_bit_cast(unsigned,
                     pack2(__builtin_amdgcn_rcpf(acc[2 * k]),
                           __builtin_amdgcn_rcpf(acc[2 * k + 1])));
    }
    // x = r (app 200); w = window of c (app 199)

    // ---- epilogue: out_row = r_a * sum_{gc<K} K[a][gc] c_gc ----
    unsigned cmask[20];
#pragma unroll
    for (int m = 0; m < 20; ++m) {
        int g0 = gbase + 2 * m, g1 = g0 + 1;
        h2 cw = __builtin_bit_cast(h2, w[m]);
        float c0 = (g0 >= 0 && g0 < KTOP) ? (float)cw[0] : 0.f;
        float c1 = (g1 >= 0 && g1 < KTOP) ? (float)cw[1] : 0.f;
        cmask[m] = __builtin_bit_cast(unsigned, pack2(c0, c1));
    }
    float accK[8] = {0.f, 0.f, 0.f, 0.f, 0.f, 0.f, 0.f, 0.f};
#pragma unroll
    for (int mb = 0; mb < 5; ++mb) {
        uint4 kc[8];
#pragma unroll
        for (int r = 0; r < 8; ++r)
            kc[r] = Kl[(r * 5 + mb) * 64];
#pragma unroll
        for (int j = 0; j < 4; ++j) {
            h2 cm = __builtin_bit_cast(h2, cmask[4 * mb + j]);
#pragma unroll
            for (int r = 0; r < 8; ++r) {
                unsigned kd = (j == 0) ? kc[r].x : (j == 1) ? kc[r].y
                            : (j == 2) ? kc[r].z : kc[r].w;
                accK[r] = __builtin_amdgcn_fdot2(
                            __builtin_bit_cast(h2, kd), cm, accK[r], false);
            }
        }
    }
#pragma unroll
    for (int k = 0; k < 4; ++k) {
        h2 xr = __builtin_bit_cast(h2, x[k]);
        out[b * N + ti[r0 + 2 * k]]     = (float)xr[0] * accK[2 * k];
        out[b * N + ti[r0 + 2 * k + 1]] = (float)xr[1] * accK[2 * k + 1];
    }
}

extern "C" void kernel_launch(void* const* d_in, const int* in_sizes, int n_in,
                              void* d_out, int out_size, void* d_ws, size_t ws_size,
                              hipStream_t stream) {
    const float* scores = (const float*)d_in[0];
    float* out = (float*)d_out;
    sinkhorn_topk_kernel<<<dim3(BATCH), dim3(64), 0, stream>>>(scores, out);
}

// Round 9
// 146.921 us; speedup vs baseline: 1.0973x; 1.0973x over previous
//
#include <hip/hip_runtime.h>

// Sinkhorn top-k, sorted-value domain, x <- 1/(Mx), 200 apps.
// R9: 2 waves per batch, 4 rows/lane. Per-wave fdot2 72 (was 160); K = 72
// dwords/lane -> low enough pressure to stay in arch VGPRs (kills the
// v_accvgpr_read-per-fdot2 tax R7 exposed). Window via +-4 DPP hops
// (R7-validated); only the row-256 seam crosses waves: 16-dword LDS halo,
// double-buffered by t&1, ONE barrier/app; halo reads issued post-barrier,
// consumed last (hidden under interior fdot2s).

#define N      512
#define BATCH  16
#define KTOP   50
#define NAPPS  200         // 100 iterations x (col + row) - exact iterate count
#define COEF   1442.6950408889634f   // log2(e) / EPSILON, EPSILON = 1e-3

typedef _Float16 h2 __attribute__((ext_vector_type(2)));

static __device__ __forceinline__ h2 pack2(float a, float b) {
    return __builtin_bit_cast(h2, __builtin_amdgcn_cvt_pkrtz(a, b));
}
// lane i <- lane i-1 (zero into lane 0)   [validated R7]
static __device__ __forceinline__ unsigned shr1(unsigned v) {
    return (unsigned)__builtin_amdgcn_update_dpp(0, (int)v, 0x138, 0xF, 0xF, true);
}
// lane i <- lane i+1 (zero into lane 63)  [validated R7]
static __device__ __forceinline__ unsigned shl1(unsigned v) {
    return (unsigned)__builtin_amdgcn_update_dpp(0, (int)v, 0x130, 0xF, 0xF, true);
}

__global__ __launch_bounds__(128, 1)
void sinkhorn_topk_kernel(const float* __restrict__ scores,
                          float* __restrict__ out) {
    __shared__ __align__(16) float    tv[N];      // sorted values, descending
    __shared__ int                    ti[N];      // original index per rank
    __shared__ __align__(16) unsigned xh[2][16];  // seam halo, dbuf by t&1
    // xh[buf][0..7]  = global dwords 120..127 (rows 240..255, wave0 lanes 60..63)
    // xh[buf][8..15] = global dwords 128..135 (rows 256..271, wave1 lanes 0..3)

    const int tid  = threadIdx.x;    // 0..127
    const int lane = tid & 63;
    const int wv   = tid >> 6;
    const int b    = blockIdx.x;

    ((float4*)tv)[tid] = ((const float4*)(scores + b * N))[tid];
    ((int4*)ti)[tid]   = make_int4(4 * tid, 4 * tid + 1, 4 * tid + 2, 4 * tid + 3);
    __syncthreads();

    // ---- bitonic sort, descending (R6-validated) ----
    for (int k = 2; k <= N; k <<= 1) {
        for (int j = k >> 1; j > 0; j >>= 1) {
#pragma unroll
            for (int e = 0; e < 2; ++e) {
                int q = tid + e * 128;
                int i = ((q & ~(j - 1)) << 1) | (q & (j - 1));
                int p = i | j;
                float va = tv[i], vb = tv[p];
                bool up = ((i & k) == 0);
                bool sw = up ? (va < vb) : (va > vb);
                if (sw) {
                    tv[i] = vb; tv[p] = va;
                    int t_ = ti[i]; ti[i] = ti[p]; ti[p] = t_;
                }
            }
            __syncthreads();
        }
    }

    // ---- K band: rows 4tid..4tid+3, cols (halves) 4tid-16..4tid+19 ----
    const int r0 = 4 * tid;
    const int gb = r0 - 16;
    float trow[4];
#pragma unroll
    for (int r = 0; r < 4; ++r) trow[r] = tv[r0 + r];

    h2 K2[4][18];                    // 72 dwords/lane -> arch-VGPR resident
#pragma unroll
    for (int m = 0; m < 18; ++m) {
        int g0 = gb + 2 * m, g1 = g0 + 1;
        int c0 = min(max(g0, 0), N - 1), c1 = min(max(g1, 0), N - 1);
        float s0 = tv[c0], s1 = tv[c1];
#pragma unroll
        for (int r = 0; r < 4; ++r) {
            float d0 = trow[r] - s0, d1 = trow[r] - s1;
            K2[r][m] = pack2(exp2f(-COEF * d0 * d0), exp2f(-COEF * d1 * d1));
        }
    }

    unsigned x0 = 0x3C003C00u, x1 = 0x3C003C00u;   // rows 4tid..4tid+3 = 1.0h
    unsigned w[18];

    for (int t = 0; t < NAPPS; ++t) {
        const int buf = t & 1;
        // seam lanes publish their x block
        if (wv == 0 ? (lane >= 60) : (lane < 4)) {
            int idx = (wv == 0) ? (lane - 60) * 2 : 8 + lane * 2;
            xh[buf][idx]     = x0;
            xh[buf][idx + 1] = x1;
        }
        __syncthreads();

        // DPP window build: hops -4..+4 (2 dwords each)
        unsigned m1a = shr1(x0),  m1b = shr1(x1),  p1a = shl1(x0),  p1b = shl1(x1);
        unsigned m2a = shr1(m1a), m2b = shr1(m1b), p2a = shl1(p1a), p2b = shl1(p1b);
        unsigned m3a = shr1(m2a), m3b = shr1(m2b), p3a = shl1(p2a), p3b = shl1(p2b);
        unsigned m4a = shr1(m3a), m4b = shr1(m3b), p4a = shl1(p3a), p4b = shl1(p3b);
        w[0] = m4a;  w[1] = m4b;  w[2] = m3a;  w[3] = m3b;
        w[4] = m2a;  w[5] = m2b;  w[6] = m1a;  w[7] = m1b;
        w[8] = x0;   w[9] = x1;   w[10] = p1a; w[11] = p1b;
        w[12] = p2a; w[13] = p2b; w[14] = p3a; w[15] = p3b;
        w[16] = p4a; w[17] = p4b;

        // seam halo fixups (4 lanes per wave; reads issued here, used last)
        if (wv == 0) {
#pragma unroll
            for (int h = 1; h <= 4; ++h) {
                if (lane + h >= 64) {
                    int s = lane + h - 64;            // 0..3
                    w[8 + 2 * h]     = xh[buf][8 + 2 * s];
                    w[8 + 2 * h + 1] = xh[buf][9 + 2 * s];
                }
            }
        } else {
#pragma unroll
            for (int h = 1; h <= 4; ++h) {
                if (lane < h) {
                    int s = lane - h + 4;             // 0..3
                    w[8 - 2 * h]     = xh[buf][2 * s];
                    w[8 - 2 * h + 1] = xh[buf][2 * s + 1];
                }
            }
        }

        float acc[4] = {0.f, 0.f, 0.f, 0.f};
#pragma unroll
        for (int m = 0; m < 18; ++m) {
            h2 wm = __builtin_bit_cast(h2, w[m]);
#pragma unroll
            for (int r = 0; r < 4; ++r)
                acc[r] = __builtin_amdgcn_fdot2(K2[r][m], wm, acc[r], false);
        }
        x0 = __builtin_bit_cast(unsigned,
               pack2(__builtin_amdgcn_rcpf(acc[0]), __builtin_amdgcn_rcpf(acc[1])));
        x1 = __builtin_bit_cast(unsigned,
               pack2(__builtin_amdgcn_rcpf(acc[2]), __builtin_amdgcn_rcpf(acc[3])));
    }
    // x = r (app 200); w = window of c (app 199)

    // ---- epilogue: out_row = r_a * sum_{gc<K} K[a][gc] c_gc ----
    // (lanes needing cols<50 are tid<=16 -> windows entirely within wave0: no halo)
    float accK[4] = {0.f, 0.f, 0.f, 0.f};
#pragma unroll
    for (int m = 0; m < 18; ++m) {
        int g0 = gb + 2 * m, g1 = g0 + 1;
        h2 cw = __builtin_bit_cast(h2, w[m]);
        float c0 = (g0 >= 0 && g0 < KTOP) ? (float)cw[0] : 0.f;
        float c1 = (g1 >= 0 && g1 < KTOP) ? (float)cw[1] : 0.f;
        h2 cm = pack2(c0, c1);
#pragma unroll
        for (int r = 0; r < 4; ++r)
            accK[r] = __builtin_amdgcn_fdot2(K2[r][m], cm, accK[r], false);
    }
    h2 xr0 = __builtin_bit_cast(h2, x0);
    h2 xr1 = __builtin_bit_cast(h2, x1);
    out[b * N + ti[r0 + 0]] = (float)xr0[0] * accK[0];
    out[b * N + ti[r0 + 1]] = (float)xr0[1] * accK[1];
    out[b * N + ti[r0 + 2]] = (float)xr1[0] * accK[2];
    out[b * N + ti[r0 + 3]] = (float)xr1[1] * accK[3];
}

extern "C" void kernel_launch(void* const* d_in, const int* in_sizes, int n_in,
                              void* d_out, int out_size, void* d_ws, size_t ws_size,
                              hipStream_t stream) {
    const float* scores = (const float*)d_in[0];
    float* out = (float*)d_out;
    sinkhorn_topk_kernel<<<dim3(BATCH), dim3(128), 0, stream>>>(scores, out);
}

// Round 10
// 139.350 us; speedup vs baseline: 1.1570x; 1.0543x over previous
//
#include <hip/hip_runtime.h>

// Sinkhorn top-k, sorted-value domain, x <- 1/(Mx), 200 apps.
// R10: R9 structure (2 waves/batch, 4 rows/lane, DPP window + tiny LDS seam
// halo) with two changes:
//  1) amdgpu_waves_per_eu(1,1): pins the allocator's occupancy model at
//     1 wave/EU so it stops capping arch VGPRs at a tier (R3-R9 all showed
//     K parked in AGPRs -> v_accvgpr_read per fdot2, ~72 extra insts/app).
//  2) radius 16->12: fdot2 72->56, DPP 16->12, K 72->56 dwords.
//     absmax law (edge^2): +1e-3 -> ~5e-3 total vs 2e-2 threshold.

#define N      512
#define BATCH  16
#define KTOP   50
#define NAPPS  200         // 100 iterations x (col + row) - exact iterate count
#define COEF   1442.6950408889634f   // log2(e) / EPSILON, EPSILON = 1e-3
#define NM     14          // window dwords (28 halves, radius 12)

typedef _Float16 h2 __attribute__((ext_vector_type(2)));

static __device__ __forceinline__ h2 pack2(float a, float b) {
    return __builtin_bit_cast(h2, __builtin_amdgcn_cvt_pkrtz(a, b));
}
// lane i <- lane i-1 (zero into lane 0)   [validated R7]
static __device__ __forceinline__ unsigned shr1(unsigned v) {
    return (unsigned)__builtin_amdgcn_update_dpp(0, (int)v, 0x138, 0xF, 0xF, true);
}
// lane i <- lane i+1 (zero into lane 63)  [validated R7]
static __device__ __forceinline__ unsigned shl1(unsigned v) {
    return (unsigned)__builtin_amdgcn_update_dpp(0, (int)v, 0x130, 0xF, 0xF, true);
}

__global__
__attribute__((amdgpu_flat_work_group_size(128, 128), amdgpu_waves_per_eu(1, 1)))
void sinkhorn_topk_kernel(const float* __restrict__ scores,
                          float* __restrict__ out) {
    __shared__ __align__(16) float    tv[N];      // sorted values, descending
    __shared__ int                    ti[N];      // original index per rank
    __shared__ __align__(16) unsigned xh[2][12];  // seam halo, dbuf by t&1
    // xh[buf][0..5]  = x dwords of wave0 lanes 61..63 (rows 244..255)
    // xh[buf][6..11] = x dwords of wave1 lanes 0..2   (rows 256..267)

    const int tid  = threadIdx.x;    // 0..127
    const int lane = tid & 63;
    const int wv   = tid >> 6;
    const int b    = blockIdx.x;

    ((float4*)tv)[tid] = ((const float4*)(scores + b * N))[tid];
    ((int4*)ti)[tid]   = make_int4(4 * tid, 4 * tid + 1, 4 * tid + 2, 4 * tid + 3);
    __syncthreads();

    // ---- bitonic sort, descending (R6-validated) ----
    for (int k = 2; k <= N; k <<= 1) {
        for (int j = k >> 1; j > 0; j >>= 1) {
#pragma unroll
            for (int e = 0; e < 2; ++e) {
                int q = tid + e * 128;
                int i = ((q & ~(j - 1)) << 1) | (q & (j - 1));
                int p = i | j;
                float va = tv[i], vb = tv[p];
                bool up = ((i & k) == 0);
                bool sw = up ? (va < vb) : (va > vb);
                if (sw) {
                    tv[i] = vb; tv[p] = va;
                    int t_ = ti[i]; ti[i] = ti[p]; ti[p] = t_;
                }
            }
            __syncthreads();
        }
    }

    // ---- K band: rows 4tid..4tid+3, cols (halves) 4tid-12..4tid+15 ----
    const int r0 = 4 * tid;
    const int gb = r0 - 12;
    float trow[4];
#pragma unroll
    for (int r = 0; r < 4; ++r) trow[r] = tv[r0 + r];

    h2 K2[4][NM];                    // 56 dwords/lane
#pragma unroll
    for (int m = 0; m < NM; ++m) {
        int g0 = gb + 2 * m, g1 = g0 + 1;
        int c0 = min(max(g0, 0), N - 1), c1 = min(max(g1, 0), N - 1);
        float s0 = tv[c0], s1 = tv[c1];
#pragma unroll
        for (int r = 0; r < 4; ++r) {
            float d0 = trow[r] - s0, d1 = trow[r] - s1;
            K2[r][m] = pack2(exp2f(-COEF * d0 * d0), exp2f(-COEF * d1 * d1));
        }
    }

    unsigned x0 = 0x3C003C00u, x1 = 0x3C003C00u;   // rows 4tid..4tid+3 = 1.0h
    unsigned w[NM];

    for (int t = 0; t < NAPPS; ++t) {
        const int buf = t & 1;
        // seam lanes publish their x block
        if (wv == 0 ? (lane >= 61) : (lane < 3)) {
            int idx = (wv == 0) ? (lane - 61) * 2 : 6 + lane * 2;
            xh[buf][idx]     = x0;
            xh[buf][idx + 1] = x1;
        }
        __syncthreads();

        // DPP window build: hops -3..+3 (2 dwords each)
        unsigned m1a = shr1(x0),  m1b = shr1(x1),  p1a = shl1(x0),  p1b = shl1(x1);
        unsigned m2a = shr1(m1a), m2b = shr1(m1b), p2a = shl1(p1a), p2b = shl1(p1b);
        unsigned m3a = shr1(m2a), m3b = shr1(m2b), p3a = shl1(p2a), p3b = shl1(p2b);
        w[0] = m3a;  w[1] = m3b;  w[2] = m2a;  w[3] = m2b;
        w[4] = m1a;  w[5] = m1b;  w[6] = x0;   w[7] = x1;
        w[8] = p1a;  w[9] = p1b;  w[10] = p2a; w[11] = p2b;
        w[12] = p3a; w[13] = p3b;

        // seam halo fixups (3 lanes per wave; reads here, consumed in the dots)
        if (wv == 0) {
#pragma unroll
            for (int h = 1; h <= 3; ++h) {
                if (lane + h >= 64) {
                    int s = lane + h - 64;            // 0..2
                    w[6 + 2 * h]     = xh[buf][6 + 2 * s];
                    w[7 + 2 * h]     = xh[buf][7 + 2 * s];
                }
            }
        } else {
#pragma unroll
            for (int h = 1; h <= 3; ++h) {
                if (lane < h) {
                    int s = lane - h + 3;             // 0..2
                    w[6 - 2 * h]     = xh[buf][2 * s];
                    w[7 - 2 * h]     = xh[buf][2 * s + 1];
                }
            }
        }

        float acc[4] = {0.f, 0.f, 0.f, 0.f};
#pragma unroll
        for (int m = 0; m < NM; ++m) {
            h2 wm = __builtin_bit_cast(h2, w[m]);
#pragma unroll
            for (int r = 0; r < 4; ++r)
                acc[r] = __builtin_amdgcn_fdot2(K2[r][m], wm, acc[r], false);
        }
        x0 = __builtin_bit_cast(unsigned,
               pack2(__builtin_amdgcn_rcpf(acc[0]), __builtin_amdgcn_rcpf(acc[1])));
        x1 = __builtin_bit_cast(unsigned,
               pack2(__builtin_amdgcn_rcpf(acc[2]), __builtin_amdgcn_rcpf(acc[3])));
    }
    // x = r (app 200); w = window of c (app 199)

    // ---- epilogue: out_row = r_a * sum_{gc<K} K[a][gc] c_gc ----
    // (rows needing cols<50 live in wave0 lanes <=15: windows never cross seam)
    float accK[4] = {0.f, 0.f, 0.f, 0.f};
#pragma unroll
    for (int m = 0; m < NM; ++m) {
        int g0 = gb + 2 * m, g1 = g0 + 1;
        h2 cw = __builtin_bit_cast(h2, w[m]);
        float c0 = (g0 >= 0 && g0 < KTOP) ? (float)cw[0] : 0.f;
        float c1 = (g1 >= 0 && g1 < KTOP) ? (float)cw[1] : 0.f;
        h2 cm = pack2(c0, c1);
#pragma unroll
        for (int r = 0; r < 4; ++r)
            accK[r] = __builtin_amdgcn_fdot2(K2[r][m], cm, accK[r], false);
    }
    h2 xr0 = __builtin_bit_cast(h2, x0);
    h2 xr1 = __builtin_bit_cast(h2, x1);
    out[b * N + ti[r0 + 0]] = (float)xr0[0] * accK[0];
    out[b * N + ti[r0 + 1]] = (float)xr0[1] * accK[1];
    out[b * N + ti[r0 + 2]] = (float)xr1[0] * accK[2];
    out[b * N + ti[r0 + 3]] = (float)xr1[1] * accK[3];
}

extern "C" void kernel_launch(void* const* d_in, const int* in_sizes, int n_in,
                              void* d_out, int out_size, void* d_ws, size_t ws_size,
                              hipStream_t stream) {
    const float* scores = (const float*)d_in[0];
    float* out = (float*)d_out;
    sinkhorn_topk_kernel<<<dim3(BATCH), dim3(128), 0, stream>>>(scores, out);
}

// Round 11
// 138.961 us; speedup vs baseline: 1.1602x; 1.0028x over previous
//
#include <hip/hip_runtime.h>

// Sinkhorn top-k, sorted-value domain, x <- 1/(Mx), 200 apps.
// R11 = R7 (single wave per batch: zero barriers / zero LDS in the loop)
//     + R10's amdgpu_waves_per_eu(1,1) (keeps the K band in ARCH VGPRs --
//       R7's 104us was the v_accvgpr_read-per-fdot2 tax, proven by R10's
//       VGPR_Count 60->132 + time drop when the attribute landed).
// 8 rows/lane, radius 12: K2 = 8x16 dwords, window = 16 dwords via 12 DPP
// (+-2 lane hops, zero-fill = band truncation). Per app: ~155 VALU insts,
// 8 independent fdot2 chains, no lgkmcnt, no s_barrier.

#define N      512
#define BATCH  16
#define KTOP   50
#define NAPPS  200         // 100 iterations x (col + row) - exact iterate count
#define COEF   1442.6950408889634f   // log2(e) / EPSILON, EPSILON = 1e-3

typedef _Float16 h2 __attribute__((ext_vector_type(2)));

static __device__ __forceinline__ h2 pack2(float a, float b) {
    return __builtin_bit_cast(h2, __builtin_amdgcn_cvt_pkrtz(a, b));
}
// lane i <- lane i-1 (zero into lane 0)   [validated R7]
static __device__ __forceinline__ unsigned shr1(unsigned v) {
    return (unsigned)__builtin_amdgcn_update_dpp(0, (int)v, 0x138, 0xF, 0xF, true);
}
// lane i <- lane i+1 (zero into lane 63)  [validated R7]
static __device__ __forceinline__ unsigned shl1(unsigned v) {
    return (unsigned)__builtin_amdgcn_update_dpp(0, (int)v, 0x130, 0xF, 0xF, true);
}

__global__
__attribute__((amdgpu_flat_work_group_size(64, 64), amdgpu_waves_per_eu(1, 1)))
void sinkhorn_topk_kernel(const float* __restrict__ scores,
                          float* __restrict__ out) {
    __shared__ __align__(16) float tv[N];   // sorted values, descending
    __shared__ int                 ti[N];   // original index of each rank

    const int lane = threadIdx.x;           // 0..63
    const int b    = blockIdx.x;

    ((float4*)tv)[2 * lane]     = ((const float4*)(scores + b * N))[2 * lane];
    ((float4*)tv)[2 * lane + 1] = ((const float4*)(scores + b * N))[2 * lane + 1];
#pragma unroll
    for (int r = 0; r < 8; ++r) ti[8 * lane + r] = 8 * lane + r;
    __syncthreads();

    // ---- bitonic sort, descending; 64 lanes x 4 compare-exchanges/step ----
    for (int k = 2; k <= N; k <<= 1) {
        for (int j = k >> 1; j > 0; j >>= 1) {
#pragma unroll
            for (int e = 0; e < 4; ++e) {
                int q = lane + e * 64;                 // pair id 0..255
                int i = ((q & ~(j - 1)) << 1) | (q & (j - 1));
                int p = i | j;
                float va = tv[i], vb = tv[p];
                bool up = ((i & k) == 0);
                bool sw = up ? (va < vb) : (va > vb);
                if (sw) {
                    tv[i] = vb; tv[p] = va;
                    int t_ = ti[i]; ti[i] = ti[p]; ti[p] = t_;
                }
            }
            __syncthreads();
        }
    }

    // ---- K band: rows 8l..8l+7, cols (halves) 8l-12..8l+19 (16 dwords) ----
    const int r0 = 8 * lane;
    const int gb = r0 - 12;
    float trow[8];
#pragma unroll
    for (int r = 0; r < 8; ++r) trow[r] = tv[r0 + r];

    h2 K2[8][16];                           // 128 dwords/lane, arch-VGPR
#pragma unroll
    for (int d = 0; d < 16; ++d) {
        int g0 = gb + 2 * d, g1 = g0 + 1;
        int c0 = min(max(g0, 0), N - 1), c1 = min(max(g1, 0), N - 1);
        float s0 = tv[c0], s1 = tv[c1];
#pragma unroll
        for (int r = 0; r < 8; ++r) {
            float d0 = trow[r] - s0, d1 = trow[r] - s1;
            K2[r][d] = pack2(exp2f(-COEF * d0 * d0), exp2f(-COEF * d1 * d1));
        }
    }

    // ---- iterate in registers: x fp16, 8 rows/lane = 4 dwords ----
    unsigned x[4] = {0x3C003C00u, 0x3C003C00u, 0x3C003C00u, 0x3C003C00u};
    unsigned w[16];   // window dwords: global dwords 4l-6 .. 4l+9

    for (int t = 0; t < NAPPS; ++t) {
        unsigned s1a = shr1(x[0]), s1b = shr1(x[1]);
        unsigned s1c = shr1(x[2]), s1d = shr1(x[3]);
        unsigned l1a = shl1(x[0]), l1b = shl1(x[1]);
        unsigned l1c = shl1(x[2]), l1d = shl1(x[3]);
        w[0] = shr1(s1c);  w[1] = shr1(s1d);          // lane l-2, dwords 2,3
        w[2] = s1a;  w[3] = s1b;  w[4] = s1c;  w[5] = s1d;   // lane l-1
        w[6] = x[0]; w[7] = x[1]; w[8] = x[2]; w[9] = x[3];  // own
        w[10] = l1a; w[11] = l1b; w[12] = l1c; w[13] = l1d;  // lane l+1
        w[14] = shl1(l1a); w[15] = shl1(l1b);         // lane l+2, dwords 0,1

        float acc[8] = {0.f, 0.f, 0.f, 0.f, 0.f, 0.f, 0.f, 0.f};
#pragma unroll
        for (int d = 0; d < 16; ++d) {
            h2 wm = __builtin_bit_cast(h2, w[d]);
#pragma unroll
            for (int r = 0; r < 8; ++r)
                acc[r] = __builtin_amdgcn_fdot2(K2[r][d], wm, acc[r], false);
        }
#pragma unroll
        for (int k = 0; k < 4; ++k)
            x[k] = __builtin_bit_cast(unsigned,
                     pack2(__builtin_amdgcn_rcpf(acc[2 * k]),
                           __builtin_amdgcn_rcpf(acc[2 * k + 1])));
    }
    // x = r (app 200); w = window of c (app 199)

    // ---- epilogue: out_row = r_a * sum_{gc<K} K[a][gc] c_gc ----
    float accK[8] = {0.f, 0.f, 0.f, 0.f, 0.f, 0.f, 0.f, 0.f};
#pragma unroll
    for (int d = 0; d < 16; ++d) {
        int g0 = gb + 2 * d, g1 = g0 + 1;
        h2 cw = __builtin_bit_cast(h2, w[d]);
        float c0 = (g0 >= 0 && g0 < KTOP) ? (float)cw[0] : 0.f;
        float c1 = (g1 >= 0 && g1 < KTOP) ? (float)cw[1] : 0.f;
        h2 cm = pack2(c0, c1);
#pragma unroll
        for (int r = 0; r < 8; ++r)
            accK[r] = __builtin_amdgcn_fdot2(K2[r][d], cm, accK[r], false);
    }
#pragma unroll
    for (int k = 0; k < 4; ++k) {
        h2 xr = __builtin_bit_cast(h2, x[k]);
        out[b * N + ti[r0 + 2 * k]]     = (float)xr[0] * accK[2 * k];
        out[b * N + ti[r0 + 2 * k + 1]] = (float)xr[1] * accK[2 * k + 1];
    }
}

extern "C" void kernel_launch(void* const* d_in, const int* in_sizes, int n_in,
                              void* d_out, int out_size, void* d_ws, size_t ws_size,
                              hipStream_t stream) {
    const float* scores = (const float*)d_in[0];
    float* out = (float*)d_out;
    sinkhorn_topk_kernel<<<dim3(BATCH), dim3(64), 0, stream>>>(scores, out);
}

// Round 12
// 131.357 us; speedup vs baseline: 1.2274x; 1.0579x over previous
//
#include <hip/hip_runtime.h>

// Sinkhorn top-k, sorted-value domain, x <- 1/(Mx), 200 apps.
// R12 = R11 (1 wave/batch, DPP window, waves_per_eu(1,1)) +
//  1) radius 12->10: window 14 dwords, fdot2 128->112 (edge^2 law: +8.6e-3)
//  2) split-half app body: rows 0-3 dots -> their rcp/pack/DPP overlap
//     rows 4-7 dots; only the tail funnel (~80cyc) stays serial.
//  3) w rebuilt at loop END; last app peeled so epilogue keeps c=app-199
//     window while x=app-200 (same iterate semantics as R11).

#define N      512
#define BATCH  16
#define KTOP   50
#define NAPPS  200
#define ND     14          // window dwords: global dwords 4l-5 .. 4l+8
#define COEF   1442.6950408889634f   // log2(e)/EPSILON, EPSILON=1e-3
#define ONEH2  0x3C003C00u

typedef _Float16 h2 __attribute__((ext_vector_type(2)));

static __device__ __forceinline__ h2 pack2(float a, float b) {
    return __builtin_bit_cast(h2, __builtin_amdgcn_cvt_pkrtz(a, b));
}
static __device__ __forceinline__ unsigned shr1(unsigned v) {   // lane i <- i-1, 0-fill
    return (unsigned)__builtin_amdgcn_update_dpp(0, (int)v, 0x138, 0xF, 0xF, true);
}
static __device__ __forceinline__ unsigned shl1(unsigned v) {   // lane i <- i+1, 0-fill
    return (unsigned)__builtin_amdgcn_update_dpp(0, (int)v, 0x130, 0xF, 0xF, true);
}

__global__
__attribute__((amdgpu_flat_work_group_size(64, 64), amdgpu_waves_per_eu(1, 1)))
void sinkhorn_topk_kernel(const float* __restrict__ scores,
                          float* __restrict__ out) {
    __shared__ __align__(16) float tv[N];
    __shared__ int                 ti[N];

    const int lane = threadIdx.x;           // 0..63
    const int b    = blockIdx.x;

    ((float4*)tv)[2 * lane]     = ((const float4*)(scores + b * N))[2 * lane];
    ((float4*)tv)[2 * lane + 1] = ((const float4*)(scores + b * N))[2 * lane + 1];
#pragma unroll
    for (int r = 0; r < 8; ++r) ti[8 * lane + r] = 8 * lane + r;
    __syncthreads();

    // ---- bitonic sort, descending ----
    for (int k = 2; k <= N; k <<= 1) {
        for (int j = k >> 1; j > 0; j >>= 1) {
#pragma unroll
            for (int e = 0; e < 4; ++e) {
                int q = lane + e * 64;
                int i = ((q & ~(j - 1)) << 1) | (q & (j - 1));
                int p = i | j;
                float va = tv[i], vb = tv[p];
                bool up = ((i & k) == 0);
                bool sw = up ? (va < vb) : (va > vb);
                if (sw) {
                    tv[i] = vb; tv[p] = va;
                    int t_ = ti[i]; ti[i] = ti[p]; ti[p] = t_;
                }
            }
            __syncthreads();
        }
    }

    // ---- K band: rows 8l..8l+7, col halves 8l-10..8l+17 (14 dwords) ----
    const int r0 = 8 * lane;
    const int gb = r0 - 10;
    float trow[8];
#pragma unroll
    for (int r = 0; r < 8; ++r) trow[r] = tv[r0 + r];

    h2 K2[8][ND];                           // 112 dwords/lane
#pragma unroll
    for (int d = 0; d < ND; ++d) {
        int g0 = gb + 2 * d, g1 = g0 + 1;
        int c0 = min(max(g0, 0), N - 1), c1 = min(max(g1, 0), N - 1);
        float s0 = tv[c0], s1 = tv[c1];
#pragma unroll
        for (int r = 0; r < 8; ++r) {
            float d0 = trow[r] - s0, d1 = trow[r] - s1;
            K2[r][d] = pack2(exp2f(-COEF * d0 * d0), exp2f(-COEF * d1 * d1));
        }
    }

    // ---- x (app 0) and its window ----
    unsigned x0 = ONEH2, x1 = ONEH2, x2 = ONEH2, x3 = ONEH2;
    unsigned w[ND];
    {
        unsigned s1a = shr1(x0), s1b = shr1(x1), s1c = shr1(x2), s1d = shr1(x3);
        unsigned l1a = shl1(x0), l1b = shl1(x1), l1c = shl1(x2), l1d = shl1(x3);
        w[0] = shr1(s1d);
        w[1] = s1a;  w[2] = s1b;  w[3] = s1c;  w[4] = s1d;
        w[5] = x0;   w[6] = x1;   w[7] = x2;   w[8] = x3;
        w[9] = l1a;  w[10] = l1b; w[11] = l1c; w[12] = l1d;
        w[13] = shl1(l1a);
    }

    // ---- 199 full apps (dots + rebuild), then 1 peeled app ----
    for (int t = 0; t < NAPPS - 1; ++t) {
        // half 1: rows 0..3
        float a0 = 0.f, a1 = 0.f, a2 = 0.f, a3 = 0.f;
#pragma unroll
        for (int d = 0; d < ND; ++d) {
            h2 wm = __builtin_bit_cast(h2, w[d]);
            a0 = __builtin_amdgcn_fdot2(K2[0][d], wm, a0, false);
            a1 = __builtin_amdgcn_fdot2(K2[1][d], wm, a1, false);
            a2 = __builtin_amdgcn_fdot2(K2[2][d], wm, a2, false);
            a3 = __builtin_amdgcn_fdot2(K2[3][d], wm, a3, false);
        }
        unsigned nx0 = __builtin_bit_cast(unsigned,
            pack2(__builtin_amdgcn_rcpf(a0), __builtin_amdgcn_rcpf(a1)));
        unsigned nx1 = __builtin_bit_cast(unsigned,
            pack2(__builtin_amdgcn_rcpf(a2), __builtin_amdgcn_rcpf(a3)));
        unsigned ns1a = shr1(nx0), ns1b = shr1(nx1);
        unsigned nl1a = shl1(nx0), nl1b = shl1(nx1);
        unsigned nw13 = shl1(nl1a);

        // half 2: rows 4..7 (overlaps half-1 funnel)
        float a4 = 0.f, a5 = 0.f, a6 = 0.f, a7 = 0.f;
#pragma unroll
        for (int d = 0; d < ND; ++d) {
            h2 wm = __builtin_bit_cast(h2, w[d]);
            a4 = __builtin_amdgcn_fdot2(K2[4][d], wm, a4, false);
            a5 = __builtin_amdgcn_fdot2(K2[5][d], wm, a5, false);
            a6 = __builtin_amdgcn_fdot2(K2[6][d], wm, a6, false);
            a7 = __builtin_amdgcn_fdot2(K2[7][d], wm, a7, false);
        }
        unsigned nx2 = __builtin_bit_cast(unsigned,
            pack2(__builtin_amdgcn_rcpf(a4), __builtin_amdgcn_rcpf(a5)));
        unsigned nx3 = __builtin_bit_cast(unsigned,
            pack2(__builtin_amdgcn_rcpf(a6), __builtin_amdgcn_rcpf(a7)));
        unsigned ns1c = shr1(nx2), ns1d = shr1(nx3);
        unsigned nl1c = shl1(nx2), nl1d = shl1(nx3);

        x0 = nx0; x1 = nx1; x2 = nx2; x3 = nx3;
        w[0] = shr1(ns1d);
        w[1] = ns1a;  w[2] = ns1b;  w[3] = ns1c;  w[4] = ns1d;
        w[5] = nx0;   w[6] = nx1;   w[7] = nx2;   w[8] = nx3;
        w[9] = nl1a;  w[10] = nl1b; w[11] = nl1c; w[12] = nl1d;
        w[13] = nw13;
    }
    // peeled app 200: update x only; w stays = window of app-199 state (c)
    {
        float a[8] = {0.f, 0.f, 0.f, 0.f, 0.f, 0.f, 0.f, 0.f};
#pragma unroll
        for (int d = 0; d < ND; ++d) {
            h2 wm = __builtin_bit_cast(h2, w[d]);
#pragma unroll
            for (int r = 0; r < 8; ++r)
                a[r] = __builtin_amdgcn_fdot2(K2[r][d], wm, a[r], false);
        }
        x0 = __builtin_bit_cast(unsigned,
            pack2(__builtin_amdgcn_rcpf(a[0]), __builtin_amdgcn_rcpf(a[1])));
        x1 = __builtin_bit_cast(unsigned,
            pack2(__builtin_amdgcn_rcpf(a[2]), __builtin_amdgcn_rcpf(a[3])));
        x2 = __builtin_bit_cast(unsigned,
            pack2(__builtin_amdgcn_rcpf(a[4]), __builtin_amdgcn_rcpf(a[5])));
        x3 = __builtin_bit_cast(unsigned,
            pack2(__builtin_amdgcn_rcpf(a[6]), __builtin_amdgcn_rcpf(a[7])));
    }

    // ---- epilogue: out_row = r_a * sum_{gc<K} K[a][gc] c_gc ----
    float accK[8] = {0.f, 0.f, 0.f, 0.f, 0.f, 0.f, 0.f, 0.f};
#pragma unroll
    for (int d = 0; d < ND; ++d) {
        int g0 = gb + 2 * d, g1 = g0 + 1;
        h2 cw = __builtin_bit_cast(h2, w[d]);
        float c0 = (g0 >= 0 && g0 < KTOP) ? (float)cw[0] : 0.f;
        float c1 = (g1 >= 0 && g1 < KTOP) ? (float)cw[1] : 0.f;
        h2 cm = pack2(c0, c1);
#pragma unroll
        for (int r = 0; r < 8; ++r)
            accK[r] = __builtin_amdgcn_fdot2(K2[r][d], cm, accK[r], false);
    }
    unsigned xs[4] = {x0, x1, x2, x3};
#pragma unroll
    for (int k = 0; k < 4; ++k) {
        h2 xr = __builtin_bit_cast(h2, xs[k]);
        out[b * N + ti[r0 + 2 * k]]     = (float)xr[0] * accK[2 * k];
        out[b * N + ti[r0 + 2 * k + 1]] = (float)xr[1] * accK[2 * k + 1];
    }
}

extern "C" void kernel_launch(void* const* d_in, const int* in_sizes, int n_in,
                              void* d_out, int out_size, void* d_ws, size_t ws_size,
                              hipStream_t stream) {
    const float* scores = (const float*)d_in[0];
    float* out = (float*)d_out;
    sinkhorn_topk_kernel<<<dim3(BATCH), dim3(64), 0, stream>>>(scores, out);
}